// Round 2
// baseline (411.598 us; speedup 1.0000x reference)
//
#include <hip/hip_runtime.h>
#include <hip/hip_cooperative_groups.h>
#include <math.h>

namespace cg = cooperative_groups;

#define NN 4096
#define DD 512
#define INV_TAU 5.0f
#define EPSV 1e-15f

typedef unsigned short u16;
typedef __attribute__((ext_vector_type(8))) short short8;
typedef __attribute__((ext_vector_type(4))) float f32x4;

__device__ __forceinline__ void gld16(const void* g, void* l) {
  __builtin_amdgcn_global_load_lds(
      (const __attribute__((address_space(1))) unsigned int*)g,
      (__attribute__((address_space(3))) unsigned int*)l, 16, 0, 0);
}

// counted-vmcnt barriers (T3/T4): keep the newest prefetch loads in flight
// across the barrier; never drain to 0 in the main loop.
__device__ __forceinline__ void bar_vm4() {
  asm volatile("s_waitcnt vmcnt(4) lgkmcnt(0)\n\ts_barrier" ::: "memory");
}
__device__ __forceinline__ void bar_vm2() {
  asm volatile("s_waitcnt vmcnt(2) lgkmcnt(0)\n\ts_barrier" ::: "memory");
}
__device__ __forceinline__ void bar_vm1() {
  asm volatile("s_waitcnt vmcnt(1) lgkmcnt(0)\n\ts_barrier" ::: "memory");
}
__device__ __forceinline__ void bar_vm0() {
  asm volatile("s_waitcnt vmcnt(0) lgkmcnt(0)\n\ts_barrier" ::: "memory");
}

__device__ __forceinline__ float bf2f(u16 u) {
  return __uint_as_float(((unsigned)u) << 16);
}
__device__ __forceinline__ u16 f2bf(float x) {  // RNE
  unsigned u = __float_as_uint(x);
  u += 0x7fff + ((u >> 16) & 1);
  return (u16)(u >> 16);
}

__device__ __forceinline__ float wave_sum(float v) {
#pragma unroll
  for (int o = 32; o > 0; o >>= 1) v += __shfl_down(v, o, 64);
  return v;
}

// ------------- fp32 -> bf16 convert, four sources -> contiguous dst ----------
// sources concatenated a|b|c|d2 (sizes in float4 units) -> o
__global__ __launch_bounds__(256) void tobf16_4(
    const float* __restrict__ a, const float* __restrict__ b,
    const float* __restrict__ c, const float* __restrict__ d2,
    u16* __restrict__ o, int na, int nb, int nc) {
  const int i = blockIdx.x * 256 + threadIdx.x;
  int j = i;
  const float* s;
  if (j < na) {
    s = a + (size_t)j * 4;
  } else {
    j -= na;
    if (j < nb) {
      s = b + (size_t)j * 4;
    } else {
      j -= nb;
      if (j < nc) {
        s = c + (size_t)j * 4;
      } else {
        j -= nc;
        s = d2 + (size_t)j * 4;
      }
    }
  }
  float4 v = *(const float4*)s;
  unsigned long long pk = (unsigned long long)f2bf(v.x) |
                          ((unsigned long long)f2bf(v.y) << 16) |
                          ((unsigned long long)f2bf(v.z) << 32) |
                          ((unsigned long long)f2bf(v.w) << 48);
  *(unsigned long long*)&o[(size_t)i * 4] = pk;
}

// ------------- MFMA NT GEMM, depth-3 counted-vmcnt pipeline ------------------
// out = act(A@Bw^T + bias). A:[2,4096,512] bf16, Bw:[512,512] bf16.
// tile 128(i)x64(j), 8 waves of 32x32 -> grid 512 blocks (2/CU, 16 waves/CU).
// XCD-aware decode: bid%8 = xcd; each xcd owns 4 contiguous i-bands so its
// A working set (1 MB) + B (0.5 MB) stays L2-resident.
// LDS: 3 bufs x (A 128x32 | B 64x32) = 36 KiB. XOR bank swizzle as verified r1.
template <int ACT>
__global__ __launch_bounds__(512) void gemm_mfma(
    const u16* __restrict__ A, const u16* __restrict__ Bw,
    const float* __restrict__ bias, const float* __restrict__ alpha_p,
    u16* __restrict__ out) {
  __shared__ __align__(16) u16 sh[3 * 6144];
  const int tid = threadIdx.x, w = tid >> 6, lane = tid & 63;
  const int quad = lane >> 4, m16 = lane & 15;
  const int wi = w >> 1, wj = w & 1;  // 4 i-waves x 2 j-waves, 32x32 each
  const int bid = blockIdx.x;
  const int xcd = bid & 7, idx = bid >> 3;
  const int i0 = (4 * xcd + (idx & 3)) * 128;
  const int j0 = ((idx >> 2) & 7) * 64;
  const int bz = idx >> 5;
  const u16* Ab = A + (size_t)bz * ((size_t)NN * DD);
  u16* ob = out + (size_t)bz * ((size_t)NN * DD);
  const int roff =
      (m16 >> 1) * 64 + (((((m16 & 1) << 2) | quad) ^ (m16 >> 1)) * 8);
  const int st = (lane & 7) ^ (lane >> 3);
  const int srow = 2 * (lane >> 3) + (st >> 2);
  const int scol = (st & 3) * 8;
  // staging: waves 0-3 stage A (2 gld16 each: 16-row groups 2w,2w+1),
  //          waves 4-7 stage B (1 gld16 each: group w-4)
  const u16* gs = (w < 4) ? Ab : Bw;
  const int grow0 = ((w < 4) ? i0 + 2 * w * 16 : j0 + (w - 4) * 16) + srow;
  const int doff0 = (w < 4) ? 2 * w * 512 : 4096 + (w - 4) * 512;
  auto stage = [&](int bo, int k) {
    const int kn = k * 32;
    gld16(&gs[(size_t)grow0 * DD + kn + scol], sh + bo + doff0);
    if (w < 4)
      gld16(&gs[(size_t)(grow0 + 16) * DD + kn + scol], sh + bo + doff0 + 512);
  };
  stage(0, 0);
  stage(6144, 1);
  if (w < 4) bar_vm2(); else bar_vm1();
  f32x4 acc[2][2] = {};
  int ro = 0;
  for (int kc = 0; kc < 16; ++kc) {
    if (kc <= 13) {
      int so = ro + 12288;
      if (so >= 18432) so -= 18432;
      stage(so, kc + 2);
    }
    const u16* As = sh + ro;
    const u16* Bs = sh + ro + 4096;
    short8 ar[2], br[2];
#pragma unroll
    for (int s = 0; s < 2; ++s) {
      ar[s] = *(const short8*)&As[(wi * 32 + s * 16) * 32 + roff];
      br[s] = *(const short8*)&Bs[(wj * 32 + s * 16) * 32 + roff];
    }
    __builtin_amdgcn_s_setprio(1);
#pragma unroll
    for (int si = 0; si < 2; ++si)
#pragma unroll
      for (int sj = 0; sj < 2; ++sj)
        acc[si][sj] = __builtin_amdgcn_mfma_f32_16x16x32_bf16(
            ar[si], br[sj], acc[si][sj], 0, 0, 0);
    __builtin_amdgcn_s_setprio(0);
    if (kc <= 13) {
      if (w < 4) bar_vm2(); else bar_vm1();
    } else if (kc == 14) {
      bar_vm0();
    }
    ro += 6144;
    if (ro == 18432) ro = 0;
  }
  const float al = ACT ? alpha_p[0] : 0.f;
#pragma unroll
  for (int si = 0; si < 2; ++si)
#pragma unroll
    for (int sj = 0; sj < 2; ++sj) {
      const int col = j0 + wj * 32 + sj * 16 + m16;
      const float bv = bias[col];
#pragma unroll
      for (int r = 0; r < 4; ++r) {
        const int row = i0 + wi * 32 + si * 16 + quad * 4 + r;
        float x = acc[si][sj][r] + bv;
        if (ACT) x = (x >= 0.f) ? x : al * x;
        ob[(size_t)row * DD + col] = f2bf(x);
      }
    }
}

// ---------------- row-wise L2 normalize, one wave per row (vectorized) -------
// also zeroes zbf (blocks 0..127) so no separate memset node is needed.
__global__ __launch_bounds__(256) void rownorm_bf16(const u16* __restrict__ h,
                                                    u16* __restrict__ o,
                                                    float* __restrict__ zbf) {
  const int tid = threadIdx.x;
  if (blockIdx.x < 128) zbf[blockIdx.x * 256 + tid] = 0.f;
  const int row = blockIdx.x * 4 + (tid >> 6);
  const int lane = tid & 63;
  const size_t base = (size_t)row * DD + lane * 8;
  short8 v = *(const short8*)&h[base];
  float f[8];
  float s = 0.f;
#pragma unroll
  for (int j = 0; j < 8; ++j) {
    f[j] = bf2f((u16)v[j]);
    s += f[j] * f[j];
  }
  s = wave_sum(s);
  const float inv = 1.f / fmaxf(sqrtf(__shfl(s, 0, 64)), 1e-12f);
  short8 r;
#pragma unroll
  for (int j = 0; j < 8; ++j) r[j] = (short)f2bf(f[j] * inv);
  *(short8*)&o[base] = r;
}

// ------------- fused similarity: depth-3 counted-vmcnt pipeline --------------
// UNCHANGED from r1 except: block (0,0) zeroes s1|s2|scal (1040 floats, sclr)
// which sim itself never touches -> removes the memset node.
__global__ __launch_bounds__(512) void sim_mfma(
    const u16* __restrict__ na, const u16* __restrict__ nb,
    const int* __restrict__ mask, float* __restrict__ zb,
    float* __restrict__ sclr) {
  extern __shared__ __align__(16) u16 shm[];  // 3 * 4 * 4096 u16 = 96 KiB
  const int tid = threadIdx.x;
  if (blockIdx.x == 0 && blockIdx.y == 0) {
    sclr[tid] = 0.f;
    sclr[tid + 512] = 0.f;
    if (tid < 16) sclr[1024 + tid] = 0.f;
  }
  const int w = tid >> 6, lane = tid & 63;
  const int quad = lane >> 4, m16 = lane & 15;
  const int ig = w & 3, jh = w >> 2;
  const int i0 = blockIdx.y * 128, j0 = blockIdx.x * 128;
  const int roff =
      (m16 >> 1) * 64 + (((((m16 & 1) << 2) | quad) ^ (m16 >> 1)) * 8);
  const int st = (lane & 7) ^ (lane >> 3);
  const int srow = 2 * (lane >> 3) + (st >> 2);
  const int scol = (st & 3) * 8;
  const int p = w >> 1, rh = (w & 1) * 64;
  const u16* gs = (p & 1) ? nb : na;  // panels: 0 na_i, 1 nb_i, 2 na_j, 3 nb_j
  const int gr = ((p < 2) ? i0 : j0) + rh + srow;
  u16* dst0 = shm + p * 4096 + rh * 32;
  auto stage = [&](int bo, int k) {
    const int kn = k * 32;
#pragma unroll
    for (int rr = 0; rr < 64; rr += 16)
      gld16(&gs[(size_t)(gr + rr) * DD + kn + scol], dst0 + bo + rr * 32);
  };
  stage(0, 0);
  stage(16384, 1);
  bar_vm4();
  f32x4 a11[2][4] = {}, a12[2][4] = {}, a22[2][4] = {};
  int ro = 0;
  for (int kc = 0; kc < 16; ++kc) {
    if (kc <= 13) {
      int so = ro + 32768;
      if (so >= 49152) so -= 49152;
      stage(so, kc + 2);
    }
    const u16* Ai = shm + ro;
    const u16* Bi = shm + ro + 4096;
    const u16* Aj = shm + ro + 8192;
    const u16* Bj = shm + ro + 12288;
    short8 ai0 = *(const short8*)&Ai[(ig * 32 + m16) * 32 + roff - m16 * 32 + 0];
    ai0 = *(const short8*)&Ai[(ig * 32) * 32 + roff];
    short8 ai1 = *(const short8*)&Ai[(ig * 32 + 16) * 32 + roff];
    short8 bi0 = *(const short8*)&Bi[(ig * 32) * 32 + roff];
    short8 bi1 = *(const short8*)&Bi[(ig * 32 + 16) * 32 + roff];
#pragma unroll
    for (int c = 0; c < 4; ++c) {
      short8 aj = *(const short8*)&Aj[(jh * 64 + c * 16) * 32 + roff];
      short8 bj = *(const short8*)&Bj[(jh * 64 + c * 16) * 32 + roff];
      __builtin_amdgcn_s_setprio(1);
      a11[0][c] = __builtin_amdgcn_mfma_f32_16x16x32_bf16(ai0, aj, a11[0][c], 0, 0, 0);
      a11[1][c] = __builtin_amdgcn_mfma_f32_16x16x32_bf16(ai1, aj, a11[1][c], 0, 0, 0);
      a12[0][c] = __builtin_amdgcn_mfma_f32_16x16x32_bf16(ai0, bj, a12[0][c], 0, 0, 0);
      a12[1][c] = __builtin_amdgcn_mfma_f32_16x16x32_bf16(ai1, bj, a12[1][c], 0, 0, 0);
      a22[0][c] = __builtin_amdgcn_mfma_f32_16x16x32_bf16(bi0, bj, a22[0][c], 0, 0, 0);
      a22[1][c] = __builtin_amdgcn_mfma_f32_16x16x32_bf16(bi1, bj, a22[1][c], 0, 0, 0);
      __builtin_amdgcn_s_setprio(0);
    }
    if (kc <= 13) bar_vm4();
    else if (kc == 14) bar_vm0();
    ro += 16384;
    if (ro == 49152) ro = 0;
  }
  float* rred = (float*)(shm + 16384);  // [4][128] row stats
  float* cred = rred + 512;             // [4][128] col stats
  rred[tid] = 0.f;
  rred[tid + 512] = 0.f;
  __syncthreads();
  float rs11[2][4] = {}, rm11[2][4] = {}, rs12[2][4] = {}, rm12[2][4] = {};
  float cs12[4] = {}, cm12[4] = {}, cs22[4] = {}, cm22[4] = {};
#pragma unroll
  for (int t = 0; t < 2; ++t)
#pragma unroll
    for (int c = 0; c < 4; ++c) {
      const int gj = j0 + jh * 64 + c * 16 + m16;
#pragma unroll
      for (int r = 0; r < 4; ++r) {
        const int gi = i0 + ig * 32 + t * 16 + quad * 4 + r;
        const float mv = (float)mask[(size_t)gi * NN + gj];
        const float e11 = __expf(a11[t][c][r] * INV_TAU);
        const float e12 = __expf(a12[t][c][r] * INV_TAU);
        const float e22 = __expf(a22[t][c][r] * INV_TAU);
        rs11[t][r] += e11;
        rm11[t][r] += e11 * mv;
        rs12[t][r] += e12;
        rm12[t][r] += e12 * mv;
        cs12[c] += e12;
        cm12[c] += e12 * mv;
        cs22[c] += e22;
        cm22[c] += e22 * mv;
      }
    }
#pragma unroll
  for (int t = 0; t < 2; ++t)
#pragma unroll
    for (int r = 0; r < 4; ++r) {
      float v0 = rs11[t][r], v1 = rm11[t][r], v2 = rs12[t][r], v3 = rm12[t][r];
#pragma unroll
      for (int o = 1; o < 16; o <<= 1) {
        v0 += __shfl_xor(v0, o, 64);
        v1 += __shfl_xor(v1, o, 64);
        v2 += __shfl_xor(v2, o, 64);
        v3 += __shfl_xor(v3, o, 64);
      }
      if (m16 == 0) {
        const int il = ig * 32 + t * 16 + quad * 4 + r;
        atomicAdd(&rred[0 * 128 + il], v0);
        atomicAdd(&rred[1 * 128 + il], v1);
        atomicAdd(&rred[2 * 128 + il], v2);
        atomicAdd(&rred[3 * 128 + il], v3);
      }
    }
#pragma unroll
  for (int c = 0; c < 4; ++c) {
    float v0 = cs12[c], v1 = cm12[c], v2 = cs22[c], v3 = cm22[c];
    v0 += __shfl_xor(v0, 16, 64); v0 += __shfl_xor(v0, 32, 64);
    v1 += __shfl_xor(v1, 16, 64); v1 += __shfl_xor(v1, 32, 64);
    v2 += __shfl_xor(v2, 16, 64); v2 += __shfl_xor(v2, 32, 64);
    v3 += __shfl_xor(v3, 16, 64); v3 += __shfl_xor(v3, 32, 64);
    if (lane < 16) {
      const int jl = jh * 64 + c * 16 + lane;
      atomicAdd(&cred[0 * 128 + jl], v0);
      atomicAdd(&cred[1 * 128 + jl], v1);
      atomicAdd(&cred[2 * 128 + jl], v2);
      atomicAdd(&cred[3 * 128 + jl], v3);
    }
  }
  __syncthreads();
  if (tid < 128) {
#pragma unroll
    for (int q = 0; q < 4; ++q)
      atomicAdd(&zb[q * NN + i0 + tid], rred[q * 128 + tid]);
  } else if (tid < 256) {
    const int jl = tid - 128;
#pragma unroll
    for (int q = 0; q < 4; ++q)
      atomicAdd(&zb[(4 + q) * NN + j0 + jl], cred[q * 128 + jl]);
  }
}

// ---------------- cooperative tail: lfin+colmean | mv1 | mv2 | mv3 | logsig |
// combine, separated by grid.sync(). 256 blocks x 256 thr (1/CU). ------------
__global__ __launch_bounds__(256) void tail_coop(
    const float* __restrict__ zb, const float* __restrict__ z1,
    const float* __restrict__ z2, const float* __restrict__ gw1,
    const float* __restrict__ gb1, const float* __restrict__ ga,
    const float* __restrict__ gw2, const float* __restrict__ gb2,
    const float* __restrict__ W, float* __restrict__ s1,
    float* __restrict__ s2, float* __restrict__ t1, float* __restrict__ t2,
    float* __restrict__ hg1, float* __restrict__ hg2,
    float* __restrict__ sm1, float* __restrict__ sm2,
    float* __restrict__ scal, float* __restrict__ out) {
  cg::grid_group grid = cg::this_grid();
  const int b = blockIdx.x, tid = threadIdx.x;
  const int lane = tid & 63, wid = tid >> 6;
  __shared__ float red[8], b1s[4], b2s[4];
  {  // P1a: colmean — every block sums 16 rows of z1,z2
    float a0 = 0.f, a1 = 0.f, c0 = 0.f, c1 = 0.f;
    const int r0 = b * 16;
    for (int r = r0; r < r0 + 16; ++r) {
      const size_t ro = (size_t)r * DD;
      a0 += z1[ro + tid];
      a1 += z1[ro + 256 + tid];
      c0 += z2[ro + tid];
      c1 += z2[ro + 256 + tid];
    }
    atomicAdd(&s1[tid], a0 * (1.f / NN));
    atomicAdd(&s1[tid + 256], a1 * (1.f / NN));
    atomicAdd(&s2[tid], c0 * (1.f / NN));
    atomicAdd(&s2[tid + 256], c1 * (1.f / NN));
  }
  if (b >= 64 && b < 80) {  // P1b: local InfoNCE finalize (4096 elems)
    const int i = (b - 64) * 256 + tid;
    const float r11 = zb[i], r11m = zb[NN + i];
    const float r12 = zb[2 * NN + i], r12m = zb[3 * NN + i];
    const float c12 = zb[4 * NN + i], c12m = zb[5 * NN + i];
    const float c22 = zb[6 * NN + i], c22m = zb[7 * NN + i];
    float l1 = -logf(r12m / (r11 + r12 - r11m));
    float l2 = -logf(c12m / (c22 + c12 - c22m));
    l1 = wave_sum(l1);
    l2 = wave_sum(l2);
    if (lane == 0) { b1s[wid] = l1; b2s[wid] = l2; }
    __syncthreads();
    if (tid == 0) {
      atomicAdd(&scal[0], b1s[0] + b1s[1] + b1s[2] + b1s[3]);
      atomicAdd(&scal[1], b2s[0] + b2s[1] + b2s[2] + b2s[3]);
    }
  }
  grid.sync();
  const int gw = b * 4 + wid;  // 1024 waves == 512 rows x 2 batches
  const int row = gw & 511, bt = gw >> 9;
  {  // P2: t = prelu(gw1 @ s + gb1)
    const float* x = bt ? s2 : s1;
    float* y = bt ? t2 : t1;
    float acc = 0.f;
#pragma unroll
    for (int t = 0; t < 8; ++t)
      acc = fmaf(gw1[(size_t)row * DD + lane + 64 * t], x[lane + 64 * t], acc);
    acc = wave_sum(acc);
    if (lane == 0) {
      acc += gb1[row];
      const float al = ga[0];
      y[row] = (acc >= 0.f) ? acc : al * acc;
    }
  }
  grid.sync();
  {  // P3: hg = gw2 @ t + gb2
    const float* x = bt ? t2 : t1;
    float* y = bt ? hg2 : hg1;
    float acc = 0.f;
#pragma unroll
    for (int t = 0; t < 8; ++t)
      acc = fmaf(gw2[(size_t)row * DD + lane + 64 * t], x[lane + 64 * t], acc);
    acc = wave_sum(acc);
    if (lane == 0) y[row] = acc + gb2[row];
  }
  grid.sync();
  {  // P4: summ = W @ hg
    const float* x = bt ? hg2 : hg1;
    float* y = bt ? sm2 : sm1;
    float acc = 0.f;
#pragma unroll
    for (int t = 0; t < 8; ++t)
      acc = fmaf(W[(size_t)row * DD + lane + 64 * t], x[lane + 64 * t], acc);
    acc = wave_sum(acc);
    if (lane == 0) y[row] = acc;
  }
  grid.sync();
  {  // P5: logsig reduce — each wave handles 8 rows of its batch
    const float* z = bt ? z2 : z1;
    const float* sp = bt ? sm2 : sm1;
    const float* sn = bt ? sm1 : sm2;
    float lp = 0.f, ln_ = 0.f;
#pragma unroll
    for (int k = 0; k < 8; ++k) {
      const int rr = row + 512 * k;
      float dp = 0.f, dn = 0.f;
#pragma unroll
      for (int t = 0; t < 8; ++t) {
        const float zv = z[(size_t)rr * DD + lane + 64 * t];
        dp = fmaf(zv, sp[lane + 64 * t], dp);
        dn = fmaf(zv, sn[lane + 64 * t], dn);
      }
      dp = wave_sum(dp);
      dn = wave_sum(dn);
      if (lane == 0) {
        lp += -logf(1.f / (1.f + __expf(-dp)) + EPSV);
        ln_ += -logf(1.f - 1.f / (1.f + __expf(-dn)) + EPSV);
      }
    }
    if (lane == 0) { red[wid] = lp; red[4 + wid] = ln_; }
    __syncthreads();
    if (tid == 0) {
      atomicAdd(bt ? &scal[4] : &scal[2], red[0] + red[1] + red[2] + red[3]);
      atomicAdd(bt ? &scal[3] : &scal[5], red[4] + red[5] + red[6] + red[7]);
    }
  }
  grid.sync();
  if (b == 0 && tid == 0) {  // P6: combine
    const float local = 0.5f * (scal[0] + scal[1]) * (1.f / NN);
    const float glob =
        0.25f * (scal[2] + scal[3] + scal[4] + scal[5]) * (1.f / NN);
    out[0] = 0.5f * local + 0.5f * glob;
  }
}

// ---------------- fallback discrete kernels (if coop launch fails) -----------
__global__ __launch_bounds__(256) void k_lfcm(const float* __restrict__ zb,
                                              const float* __restrict__ z1,
                                              const float* __restrict__ z2,
                                              float* __restrict__ s1,
                                              float* __restrict__ s2,
                                              float* __restrict__ scal) {
  const int b = blockIdx.x, tid = threadIdx.x;
  const int lane = tid & 63, wid = tid >> 6;
  __shared__ float b1s[4], b2s[4];
  float a0 = 0.f, a1 = 0.f, c0 = 0.f, c1 = 0.f;
  const int r0 = b * 16;
  for (int r = r0; r < r0 + 16; ++r) {
    const size_t ro = (size_t)r * DD;
    a0 += z1[ro + tid];
    a1 += z1[ro + 256 + tid];
    c0 += z2[ro + tid];
    c1 += z2[ro + 256 + tid];
  }
  atomicAdd(&s1[tid], a0 * (1.f / NN));
  atomicAdd(&s1[tid + 256], a1 * (1.f / NN));
  atomicAdd(&s2[tid], c0 * (1.f / NN));
  atomicAdd(&s2[tid + 256], c1 * (1.f / NN));
  if (b >= 64 && b < 80) {
    const int i = (b - 64) * 256 + tid;
    const float r11 = zb[i], r11m = zb[NN + i];
    const float r12 = zb[2 * NN + i], r12m = zb[3 * NN + i];
    const float c12 = zb[4 * NN + i], c12m = zb[5 * NN + i];
    const float c22 = zb[6 * NN + i], c22m = zb[7 * NN + i];
    float l1 = -logf(r12m / (r11 + r12 - r11m));
    float l2 = -logf(c12m / (c22 + c12 - c22m));
    l1 = wave_sum(l1);
    l2 = wave_sum(l2);
    if (lane == 0) { b1s[wid] = l1; b2s[wid] = l2; }
    __syncthreads();
    if (tid == 0) {
      atomicAdd(&scal[0], b1s[0] + b1s[1] + b1s[2] + b1s[3]);
      atomicAdd(&scal[1], b2s[0] + b2s[1] + b2s[2] + b2s[3]);
    }
  }
}

__global__ __launch_bounds__(256) void matvec2(
    const float* __restrict__ M, const float* __restrict__ x1,
    const float* __restrict__ x2, const float* __restrict__ bias,
    const float* __restrict__ alpha_p, int act, float* __restrict__ y1,
    float* __restrict__ y2) {
  const float* x = blockIdx.y ? x2 : x1;
  float* y = blockIdx.y ? y2 : y1;
  const int row = (blockIdx.x * 256 + threadIdx.x) >> 6;
  const int lane = threadIdx.x & 63;
  float acc = 0.f;
#pragma unroll
  for (int t = 0; t < 8; ++t)
    acc = fmaf(M[(size_t)row * DD + lane + 64 * t], x[lane + 64 * t], acc);
  acc = wave_sum(acc);
  if (lane == 0) {
    if (bias) acc += bias[row];
    if (act) { const float al = alpha_p[0]; acc = (acc >= 0.f) ? acc : al * acc; }
    y[row] = acc;
  }
}

__global__ __launch_bounds__(256) void logsig2(
    const float* __restrict__ z1, const float* __restrict__ z2,
    const float* __restrict__ sm1, const float* __restrict__ sm2,
    float* __restrict__ scal) {
  const int ch = blockIdx.y;
  const float* z = ch ? z2 : z1;
  const float* sp = ch ? sm2 : sm1;
  const float* sn = ch ? sm1 : sm2;
  float* accP = ch ? &scal[4] : &scal[2];
  float* accN = ch ? &scal[3] : &scal[5];
  const int lane = threadIdx.x & 63;
  const int wid = threadIdx.x >> 6;
  const int row = blockIdx.x * 4 + wid;
  float dp = 0.f, dn = 0.f;
#pragma unroll
  for (int t = 0; t < 8; ++t) {
    const float zv = z[(size_t)row * DD + lane + 64 * t];
    dp = fmaf(zv, sp[lane + 64 * t], dp);
    dn = fmaf(zv, sn[lane + 64 * t], dn);
  }
  dp = wave_sum(dp);
  dn = wave_sum(dn);
  __shared__ float bp[4], bn[4];
  if (lane == 0) {
    const float sg = 1.f / (1.f + __expf(-dp));
    bp[wid] = -logf(sg + EPSV);
    const float sg2 = 1.f / (1.f + __expf(-dn));
    bn[wid] = -logf(1.f - sg2 + EPSV);
  }
  __syncthreads();
  if (threadIdx.x == 0) {
    atomicAdd(accP, bp[0] + bp[1] + bp[2] + bp[3]);
    atomicAdd(accN, bn[0] + bn[1] + bn[2] + bn[3]);
  }
}

__global__ void combine(const float* __restrict__ scal, float* __restrict__ out) {
  const float local = 0.5f * (scal[0] + scal[1]) * (1.f / NN);
  const float glob = 0.25f * (scal[2] + scal[3] + scal[4] + scal[5]) * (1.f / NN);
  out[0] = 0.5f * local + 0.5f * glob;
}

extern "C" void kernel_launch(void* const* d_in, const int* in_sizes, int n_in,
                              void* d_out, int out_size, void* d_ws,
                              size_t ws_size, hipStream_t stream) {
  const float* z1 = (const float*)d_in[0];
  const float* z2 = (const float*)d_in[1];
  const float* lw1 = (const float*)d_in[2];
  const float* lb1 = (const float*)d_in[3];
  const float* la = (const float*)d_in[4];
  const float* lw2 = (const float*)d_in[5];
  const float* lb2 = (const float*)d_in[6];
  const float* gw1 = (const float*)d_in[7];
  const float* gb1 = (const float*)d_in[8];
  const float* ga = (const float*)d_in[9];
  const float* gw2 = (const float*)d_in[10];
  const float* gb2 = (const float*)d_in[11];
  const float* W = (const float*)d_in[12];
  const int* mask = (const int*)d_in[13];
  float* out = (float*)d_out;

  static bool attr_set = false;
  if (!attr_set) {
    (void)hipFuncSetAttribute(reinterpret_cast<const void*>(sim_mfma),
                              hipFuncAttributeMaxDynamicSharedMemorySize,
                              98304);
    attr_set = true;
  }

  const size_t ND = (size_t)NN * DD;
  u16* W1b = (u16*)d_ws;                 // [512*512] bf16
  u16* W2b = W1b + 512 * 512;
  u16* Ab = W1b + 2 * 512 * 512;         // [2][N*D] bf16
  u16* Bb = Ab + 2 * ND;                 // [2][N*D] bf16
  float* zbf = (float*)(Bb + 2 * ND);    // 8*NN
  float* s1 = zbf + 8 * NN;              // sclr region: s1|s2|scal (1040 f)
  float* s2 = s1 + DD;
  float* scal = s2 + DD;                 // [sum1,sum2,P1,Ng1,P2,Ng2]
  float* t1 = scal + 16;
  float* hg1 = t1 + DD;
  float* summ1 = hg1 + DD;
  float* t2 = summ1 + DD;
  float* hg2 = t2 + DD;
  float* summ2 = hg2 + DD;

  // 1) all fp32->bf16 conversions in one node: lw1|lw2|z1|z2
  tobf16_4<<<4608, dim3(256), 0, stream>>>(lw1, lw2, z1, z2, W1b, 65536, 65536,
                                           524288);
  // 2-3) projector GEMMs (zbf/sclr zeroing rides on later nodes)
  gemm_mfma<1><<<512, dim3(512), 0, stream>>>(Ab, W1b, lb1, la, Bb);
  gemm_mfma<0><<<512, dim3(512), 0, stream>>>(Bb, W2b, lb2, la, Ab);
  // 4) row L2-normalize (+ zero zbf)
  rownorm_bf16<<<2048, dim3(256), 0, stream>>>(Ab, Bb, zbf);
  // 5) fused similarity (+ block(0,0) zeroes s1|s2|scal)
  sim_mfma<<<dim3(NN / 128, NN / 128), dim3(512), 98304, stream>>>(
      Bb, Bb + ND, mask, zbf, s1);
  // 6) cooperative tail: local_fin+colmean -> mv1 -> mv2 -> mv3 -> logsig ->
  //    combine
  {
    void* args[19];
    args[0] = (void*)&zbf;  args[1] = (void*)&z1;   args[2] = (void*)&z2;
    args[3] = (void*)&gw1;  args[4] = (void*)&gb1;  args[5] = (void*)&ga;
    args[6] = (void*)&gw2;  args[7] = (void*)&gb2;  args[8] = (void*)&W;
    args[9] = (void*)&s1;   args[10] = (void*)&s2;  args[11] = (void*)&t1;
    args[12] = (void*)&t2;  args[13] = (void*)&hg1; args[14] = (void*)&hg2;
    args[15] = (void*)&summ1; args[16] = (void*)&summ2;
    args[17] = (void*)&scal; args[18] = (void*)&out;
    hipError_t ce = hipLaunchCooperativeKernel(
        reinterpret_cast<const void*>(tail_coop), dim3(256), dim3(256), args,
        0, stream);
    if (ce != hipSuccess) {  // fallback: discrete tail
      (void)hipGetLastError();
      k_lfcm<<<256, dim3(256), 0, stream>>>(zbf, z1, z2, s1, s2, scal);
      matvec2<<<dim3(DD / 4, 2), dim3(256), 0, stream>>>(gw1, s1, s2, gb1, ga,
                                                         1, t1, t2);
      matvec2<<<dim3(DD / 4, 2), dim3(256), 0, stream>>>(gw2, t1, t2, gb2,
                                                         nullptr, 0, hg1, hg2);
      matvec2<<<dim3(DD / 4, 2), dim3(256), 0, stream>>>(
          W, hg1, hg2, nullptr, nullptr, 0, summ1, summ2);
      logsig2<<<dim3(NN / 4, 2), dim3(256), 0, stream>>>(z1, z2, summ1, summ2,
                                                         scal);
      combine<<<1, 1, 0, stream>>>(scal, out);
    }
  }
}